// Round 13
// baseline (173.592 us; speedup 1.0000x reference)
//
#include <hip/hip_runtime.h>
#include <hip/hip_bf16.h>
#include <cstdint>

// ---------------------------------------------------------------------------
// DGNN pipeline, CSR-based aggregation (no scatter atomics on features).
// Biases gcn_b / dcn_b cancel inside the following batchnorms and are skipped.
// R5: MFMA bf16 GEMM. R6: BN folded into consumers; stats fused into props.
// R7: channel-quartered prop -> REGRESSED (XCD replication floor). Reverted.
// R8: packed esrc u32, bf16 B1/B2. R9: 8-deep gather pipeline. 199.6us.
// R10: zero_kernel (rocprof fill artifact — neutral, kept). R11: 4 nodes/wave
//      prop via 16-lane quarters + uint4 rows. 172.2us.
// R12: prop depth-8 chains (32 outstanding gathers/wave; latency-vs-fabric
//      discriminating experiment) + base-as-cursor (cursor array dropped,
//      scatter atomicAdds base to end-offset, prop start = base - count).
// ---------------------------------------------------------------------------

typedef __attribute__((ext_vector_type(8))) short bf16x8;
typedef __attribute__((ext_vector_type(4))) float f32x4;

__device__ __forceinline__ ushort f2bf(float f) {
    union { float f; unsigned u; } c; c.f = f;
    unsigned u = c.u;
    return (ushort)((u + 0x7fffu + ((u >> 16) & 1u)) >> 16);   // RNE
}
__device__ __forceinline__ unsigned pack2bf(float a, float b) {
    return (unsigned)f2bf(a) | ((unsigned)f2bf(b) << 16);
}
__device__ __forceinline__ float bflo(unsigned u) {
    union { unsigned i; float f; } c; c.i = u << 16; return c.f;
}
__device__ __forceinline__ float bfhi(unsigned u) {
    union { unsigned i; float f; } c; c.i = u & 0xffff0000u; return c.f;
}

// Grid-stride 16B zero fill.
__global__ void zero_kernel(uint4* __restrict__ p, int nwords) {
    int i = blockIdx.x * blockDim.x + threadIdx.x;
    if (i < nwords) p[i] = (uint4){0u, 0u, 0u, 0u};
}

// count destination degrees. int64 detection: odd int32 words all-zero.
__global__ void convert_kernel(const void* __restrict__ ei, int E,
                               int* __restrict__ count) {
    const int* e32 = (const int*)ei;
    bool is64 = ((e32[1] | e32[3] | e32[5] | e32[7]) == 0);
    int stride = gridDim.x * blockDim.x;
    for (int e = blockIdx.x * blockDim.x + threadIdx.x; e < E; e += stride) {
        int c = is64 ? (int)((const long long*)ei)[E + e] : e32[E + e];
        atomicAdd(&count[c], 1);
    }
}

// ---- 3-phase multi-block exclusive scan over count[N] ----
__global__ __launch_bounds__(256) void bsum_kernel(const int* __restrict__ count,
                                                   int* __restrict__ bsum, int n) {
    int t = threadIdx.x;
    int i0 = blockIdx.x * 1024 + t * 4;
    int s = 0;
    if (i0 + 4 <= n) {
        int4 v = *(const int4*)&count[i0];
        s = v.x + v.y + v.z + v.w;
    } else {
        for (int i = i0; i < n; i++) s += count[i];
    }
    __shared__ int ls[256];
    ls[t] = s;
    __syncthreads();
    for (int off = 128; off > 0; off >>= 1) {
        if (t < off) ls[t] += ls[t + off];
        __syncthreads();
    }
    if (t == 0) bsum[blockIdx.x] = ls[0];
}

__global__ void scanb_kernel(int* __restrict__ bsum, int nb) {
    __shared__ int sm[1024];
    int t = threadIdx.x;
    int v = (t < nb) ? bsum[t] : 0;
    sm[t] = v;
    __syncthreads();
    for (int off = 1; off < 1024; off <<= 1) {
        int a = (t >= off) ? sm[t - off] : 0;
        __syncthreads();
        sm[t] += a;
        __syncthreads();
    }
    if (t < nb) bsum[t] = sm[t] - v;   // exclusive
}

__global__ __launch_bounds__(256) void emit_kernel(const int* __restrict__ count,
                                                   const int* __restrict__ bbase,
                                                   int* __restrict__ base, int n) {
    int t = threadIdx.x;
    int i0 = blockIdx.x * 1024 + t * 4;
    int v[4];
    int s = 0;
    if (i0 + 4 <= n) {
        int4 q = *(const int4*)&count[i0];
        v[0] = q.x; v[1] = q.y; v[2] = q.z; v[3] = q.w;
        s = v[0] + v[1] + v[2] + v[3];
    } else {
        #pragma unroll
        for (int k = 0; k < 4; k++) {
            int i = i0 + k;
            v[k] = (i < n) ? count[i] : 0;
            s += v[k];
        }
    }
    __shared__ int sm[256];
    sm[t] = s;
    __syncthreads();
    for (int off = 1; off < 256; off <<= 1) {
        int a = (t >= off) ? sm[t - off] : 0;
        __syncthreads();
        sm[t] += a;
        __syncthreads();
    }
    int run = bbase[blockIdx.x] + sm[t] - s;
    #pragma unroll
    for (int k = 0; k < 4; k++) {
        int i = i0 + k;
        if (i < n) {
            base[i] = run;
            run += v[k];
        }
    }
}

// Emit packed (deg[src]<<24 | src*64) per destination bucket.
// base is used as the cursor: after this kernel base[c] = end offset;
// prop recovers start = base[c] - count[c].
__global__ void scatter_kernel(const void* __restrict__ ei, int E,
                               int* __restrict__ base,
                               const int* __restrict__ count,
                               unsigned* __restrict__ esrc) {
    const int* e32 = (const int*)ei;
    bool is64 = ((e32[1] | e32[3] | e32[5] | e32[7]) == 0);
    int stride = gridDim.x * blockDim.x;
    for (int e = blockIdx.x * blockDim.x + threadIdx.x; e < E; e += stride) {
        int r, c;
        if (is64) {
            r = (int)((const long long*)ei)[e];
            c = (int)((const long long*)ei)[E + e];
        } else {
            r = e32[e];
            c = e32[E + e];
        }
        int pos = atomicAdd(&base[c], 1);
        unsigned deg = (unsigned)count[r];
        esrc[pos] = (deg << 24) | ((unsigned)r << 6);
    }
}

// Both weight transposes in one launch: blocks [0,64) -> W1, [64,128) -> W2.
__global__ void wtrans_kernel(const float* __restrict__ W1, ushort* __restrict__ WT1,
                              const float* __restrict__ W2, ushort* __restrict__ WT2) {
    int b = blockIdx.x;
    const float* W = (b < 64) ? W1 : W2;
    ushort* WT = (b < 64) ? WT1 : WT2;
    int t = (b & 63) * 256 + threadIdx.x;
    int c = t >> 7, k = t & 127;
    WT[t] = f2bf(W[k * 128 + c]);
}

// Y[N][128] = bf16(affine(X)) @ bf16(W) via MFMA, output packed bf16.
__global__ __launch_bounds__(256) void gemm_mfma_kernel(const float* __restrict__ Xf,
                                                        const ushort* __restrict__ Xb,
                                                        const ushort* __restrict__ WT,
                                                        const float* __restrict__ ab,
                                                        ushort* __restrict__ Ybf, int n) {
    __shared__ ushort Wl[128 * 136];
    int t = threadIdx.x;
    for (int idx = t * 8; idx < 128 * 128; idx += 256 * 8) {
        int c = idx >> 7;
        int k = idx & 127;
        *(uint4*)&Wl[c * 136 + k] = *(const uint4*)&WT[idx];
    }
    __syncthreads();

    int wid = t >> 6;
    int lane = t & 63;
    int m0 = blockIdx.x * 64 + wid * 16;
    if (m0 >= n) return;                      // after the only barrier: safe
    int row = m0 + (lane & 15);
    int rc = row < n ? row : n - 1;           // clamp loads; stores predicated
    int kg = (lane >> 4) * 8;                 // k sub-offset: 0,8,16,24

    f32x4 acc[8];
    #pragma unroll
    for (int i = 0; i < 8; i++) acc[i] = (f32x4){0.f, 0.f, 0.f, 0.f};

    #pragma unroll
    for (int ks = 0; ks < 4; ks++) {
        int k0 = ks * 32 + kg;
        bf16x8 a;
        if (Xb) {
            uint4 q = *(const uint4*)&Xb[(size_t)rc * 128 + k0];
            float f0 = bflo(q.x), f1 = bfhi(q.x), f2 = bflo(q.y), f3 = bfhi(q.y);
            float f4 = bflo(q.z), f5 = bfhi(q.z), f6 = bflo(q.w), f7 = bfhi(q.w);
            float4 alo = *(const float4*)&ab[k0];
            float4 ahi = *(const float4*)&ab[k0 + 4];
            float4 blo = *(const float4*)&ab[128 + k0];
            float4 bhi = *(const float4*)&ab[128 + k0 + 4];
            a[0] = (short)f2bf(alo.x * f0 + blo.x);
            a[1] = (short)f2bf(alo.y * f1 + blo.y);
            a[2] = (short)f2bf(alo.z * f2 + blo.z);
            a[3] = (short)f2bf(alo.w * f3 + blo.w);
            a[4] = (short)f2bf(ahi.x * f4 + bhi.x);
            a[5] = (short)f2bf(ahi.y * f5 + bhi.y);
            a[6] = (short)f2bf(ahi.z * f6 + bhi.z);
            a[7] = (short)f2bf(ahi.w * f7 + bhi.w);
        } else {
            const float* xr = &Xf[(size_t)rc * 128];
            float4 lo = *(const float4*)&xr[k0];
            float4 hi = *(const float4*)&xr[k0 + 4];
            a[0] = (short)f2bf(lo.x); a[1] = (short)f2bf(lo.y);
            a[2] = (short)f2bf(lo.z); a[3] = (short)f2bf(lo.w);
            a[4] = (short)f2bf(hi.x); a[5] = (short)f2bf(hi.y);
            a[6] = (short)f2bf(hi.z); a[7] = (short)f2bf(hi.w);
        }
        #pragma unroll
        for (int nt = 0; nt < 8; nt++) {
            int c = nt * 16 + (lane & 15);
            bf16x8 b = *(bf16x8*)&Wl[c * 136 + k0];
            acc[nt] = __builtin_amdgcn_mfma_f32_16x16x32_bf16(a, b, acc[nt], 0, 0, 0);
        }
    }

    int ro = m0 + (lane >> 4) * 4;
    int co = lane & 15;
    #pragma unroll
    for (int nt = 0; nt < 8; nt++) {
        #pragma unroll
        for (int i = 0; i < 4; i++) {
            int r = ro + i;
            if (r < n) Ybf[(size_t)r * 128 + nt * 16 + co] = f2bf(acc[nt][i]);
        }
    }
}

// 4 nodes/wave (quarters), uint4 row parts, R12: depth-8 gather chains.
// start = base[node] - count[node] (base holds end offset after scatter).
__global__ __launch_bounds__(256) void prop_kernel(const uint4* __restrict__ XW4,
                            const int* __restrict__ base,
                            const int* __restrict__ count, const unsigned* __restrict__ esrc,
                            const uint4* __restrict__ B1q, const float* __restrict__ ab1,
                            uint4* __restrict__ outq,
                            float* __restrict__ psum, float* __restrict__ psq,
                            int n, int gate) {
    int wave4 = (int)((blockIdx.x * blockDim.x + threadIdx.x) >> 6);
    int lane = threadIdx.x & 63;
    int wid = threadIdx.x >> 6;
    int g = lane >> 4;                 // quarter 0..3
    int p = lane & 15;                 // uint4 part within row
    int node = wave4 * 4 + g;
    bool valid = node < n;
    int nc = valid ? node : n - 1;
    int b = 0, cnt = 0;
    if (valid) { cnt = count[node]; b = base[node] - cnt; }
    float din = rsqrtf((float)(cnt + 1));

    uint4 vs = XW4[(size_t)nc * 16 + p];   // self row (issued early)

    float ax[8];
    #pragma unroll
    for (int k = 0; k < 8; k++) ax[k] = 0.f;

    for (int i = 0; i < cnt; i += 8) {
        unsigned pj[8];
        uint4 vj[8];
        #pragma unroll
        for (int j = 0; j < 8; j++) {
            int e = i + j;
            pj[j] = esrc[b + (e < cnt ? e : cnt - 1)];
        }
        #pragma unroll
        for (int j = 0; j < 8; j++)
            vj[j] = XW4[((pj[j] & 0xFFFFFFu) >> 2) + p];
        #pragma unroll
        for (int j = 0; j < 8; j++) {
            float w = (i + j < cnt) ? rsqrtf((float)((pj[j] >> 24) + 1)) : 0.f;
            ax[0] += w * bflo(vj[j].x); ax[1] += w * bfhi(vj[j].x);
            ax[2] += w * bflo(vj[j].y); ax[3] += w * bfhi(vj[j].y);
            ax[4] += w * bflo(vj[j].z); ax[5] += w * bfhi(vj[j].z);
            ax[6] += w * bflo(vj[j].w); ax[7] += w * bfhi(vj[j].w);
        }
    }

    float sv[8];
    sv[0] = bflo(vs.x); sv[1] = bfhi(vs.x); sv[2] = bflo(vs.y); sv[3] = bfhi(vs.y);
    sv[4] = bflo(vs.z); sv[5] = bfhi(vs.z); sv[6] = bflo(vs.w); sv[7] = bfhi(vs.w);
    #pragma unroll
    for (int k = 0; k < 8; k++) ax[k] = din * (ax[k] + din * sv[k]);

    float vv[8];
    if (gate) {
        uint4 b1 = B1q[(size_t)nc * 16 + p];
        float bv[8];
        bv[0] = bflo(b1.x); bv[1] = bfhi(b1.x); bv[2] = bflo(b1.y); bv[3] = bfhi(b1.y);
        bv[4] = bflo(b1.z); bv[5] = bfhi(b1.z); bv[6] = bflo(b1.w); bv[7] = bfhi(b1.w);
        int c0 = p * 8;
        #pragma unroll
        for (int k = 0; k < 8; k++) {
            float h = ab1[c0 + k] * bv[k] + ab1[128 + c0 + k];
            vv[k] = ax[k] * h;
        }
    } else {
        #pragma unroll
        for (int k = 0; k < 8; k++) vv[k] = ax[k];
    }

    if (valid) {
        uint4 o;
        o.x = pack2bf(vv[0], vv[1]);
        o.y = pack2bf(vv[2], vv[3]);
        o.z = pack2bf(vv[4], vv[5]);
        o.w = pack2bf(vv[6], vv[7]);
        outq[(size_t)node * 16 + p] = o;
    } else {
        #pragma unroll
        for (int k = 0; k < 8; k++) vv[k] = 0.f;
    }

    // stats: sum across the wave's 4 quarters, then across the block's waves.
    float ss[8], qq[8];
    #pragma unroll
    for (int k = 0; k < 8; k++) { ss[k] = vv[k]; qq[k] = vv[k] * vv[k]; }
    #pragma unroll
    for (int k = 0; k < 8; k++) {
        ss[k] += __shfl_xor(ss[k], 16); qq[k] += __shfl_xor(qq[k], 16);
        ss[k] += __shfl_xor(ss[k], 32); qq[k] += __shfl_xor(qq[k], 32);
    }
    __shared__ float sm_s[4][128], sm_q[4][128];
    if (g == 0) {
        int c0 = p * 8;
        #pragma unroll
        for (int k = 0; k < 8; k++) {
            sm_s[wid][c0 + k] = ss[k];
            sm_q[wid][c0 + k] = qq[k];
        }
    }
    __syncthreads();
    if (threadIdx.x < 128) {
        int c = threadIdx.x;
        float s = sm_s[0][c] + sm_s[1][c] + sm_s[2][c] + sm_s[3][c];
        float q2 = sm_q[0][c] + sm_q[1][c] + sm_q[2][c] + sm_q[3][c];
        int slot = (blockIdx.x & 63) * 128;
        atomicAdd(&psum[slot + c], s);
        atomicAdd(&psq[slot + c], q2);
    }
}

// Collapse 64-slot partials into BN affine coefficients: ab[c]=a, ab[128+c]=b.
__global__ void reduce_ab_kernel(const float* __restrict__ psum, const float* __restrict__ psq,
                                 const float* __restrict__ g, const float* __restrict__ beta,
                                 float* __restrict__ ab, int n) {
    int c = threadIdx.x;   // 128 threads
    float s = 0.f, s2 = 0.f;
    for (int r = 0; r < 64; r++) {
        s += psum[r * 128 + c];
        s2 += psq[r * 128 + c];
    }
    float invn = 1.f / (float)n;
    float mu = s * invn;
    float var = s2 * invn - mu * mu;
    float a = g[c] * rsqrtf(var + 1e-5f);
    ab[c] = a;
    ab[128 + c] = beta[c] - mu * a;
}

// result[n] = dot(h[n], ow[0:128]) + dot(BN3(gated[n]), ow[128:256]) + ob
__global__ void final_kernel(const unsigned* __restrict__ B1bf, const unsigned* __restrict__ B2bf,
                             const float* __restrict__ ab1, const float* __restrict__ ab3,
                             const float* __restrict__ ow, const float* __restrict__ ob,
                             float* __restrict__ out, int n) {
    int wave = (int)((blockIdx.x * blockDim.x + threadIdx.x) >> 6);
    int lane = threadIdx.x & 63;
    if (wave >= n) return;
    int c0 = 2 * lane, c1 = c0 + 1;
    unsigned b1 = B1bf[(size_t)wave * 64 + lane];
    unsigned b2 = B2bf[(size_t)wave * 64 + lane];
    float h0 = ab1[c0] * bflo(b1) + ab1[128 + c0];
    float h1 = ab1[c1] * bfhi(b1) + ab1[128 + c1];
    float o0 = ab3[c0] * bflo(b2) + ab3[128 + c0];
    float o1 = ab3[c1] * bfhi(b2) + ab3[128 + c1];
    float partial = h0 * ow[c0] + h1 * ow[c1] + o0 * ow[128 + c0] + o1 * ow[128 + c1];
    #pragma unroll
    for (int off = 32; off > 0; off >>= 1) partial += __shfl_down(partial, off);
    if (lane == 0) out[wave] = partial + ob[0];
}

extern "C" void kernel_launch(void* const* d_in, const int* in_sizes, int n_in,
                              void* d_out, int out_size, void* d_ws, size_t ws_size,
                              hipStream_t stream) {
    const float* x     = (const float*)d_in[0];
    const void*  ei    = d_in[1];
    const float* gcn_w = (const float*)d_in[2];
    const float* bn1_g = (const float*)d_in[4];
    const float* bn1_b = (const float*)d_in[5];
    const float* dcn_w = (const float*)d_in[6];
    const float* bn3_g = (const float*)d_in[8];
    const float* bn3_b = (const float*)d_in[9];
    const float* out_w = (const float*)d_in[10];
    const float* out_b = (const float*)d_in[11];
    float* out = (float*)d_out;

    int N = in_sizes[0] / 128;
    int E = in_sizes[1] / 2;
    size_t N128 = (size_t)N * 128;

    ushort* Abf   = (ushort*)d_ws;           // [N*128] bf16 xw/hw
    ushort* B1bf  = Abf + N128;              // [N*128] bf16 GCN agg (pre-BN)
    ushort* B2bf  = B1bf + N128;             // [N*128] bf16 gated DegGNN out
    unsigned* esrc = (unsigned*)(B2bf + N128); // [E] packed (deg<<24)|(src*64)
    int*   base  = (int*)(esrc + E);         // [N]
    int*   bsum  = base + N;                 // [1024]
    ushort* WT1  = (ushort*)(bsum + 1024);   // [16384] bf16 gcn_w^T
    ushort* WT2  = WT1 + 16384;              // [16384] bf16 dcn_w^T
    float* ab1   = (float*)(WT2 + 16384);    // [256] BN1 a|b
    float* ab3   = ab1 + 256;                // [256] BN3 a|b
    // ---- zeroed region starts here (16B aligned by construction) ----
    int*   count  = (int*)(ab3 + 256);       // [N]
    float* psum1  = (float*)(count + N);     // [64*128]
    float* psq1   = psum1 + 8192;            // [64*128]
    float* psum3  = psq1 + 8192;             // [64*128]
    float* psq3   = psum3 + 8192;            // [64*128]

    size_t zero_bytes = (size_t)((char*)(psq3 + 8192) - (char*)count);
    int zwords = (int)(zero_bytes / 16);
    zero_kernel<<<(zwords + 255) / 256, 256, 0, stream>>>((uint4*)count, zwords);

    int egrid = (E + 255) / 256;
    if (egrid > 2048) egrid = 2048;
    int nb = (N + 1023) / 1024;  // scan blocks
    int ggrid = (N + 63) / 64;   // mfma gemm blocks
    int pgrid = (N + 15) / 16;   // prop: 4 nodes/wave, 4 waves/block
    int fgrid = (N + 3) / 4;     // final: 4 waves/block

    convert_kernel<<<egrid, 256, 0, stream>>>(ei, E, count);
    bsum_kernel<<<nb, 256, 0, stream>>>(count, bsum, N);
    scanb_kernel<<<1, 1024, 0, stream>>>(bsum, nb);
    emit_kernel<<<nb, 256, 0, stream>>>(count, bsum, base, N);
    scatter_kernel<<<egrid, 256, 0, stream>>>(ei, E, base, count, esrc);
    wtrans_kernel<<<128, 256, 0, stream>>>(gcn_w, WT1, dcn_w, WT2);

    gemm_mfma_kernel<<<ggrid, 256, 0, stream>>>(x, nullptr, WT1, nullptr, Abf, N);
    prop_kernel<<<pgrid, 256, 0, stream>>>((const uint4*)Abf, base, count, esrc,
                                           nullptr, nullptr, (uint4*)B1bf,
                                           psum1, psq1, N, 0);
    reduce_ab_kernel<<<1, 128, 0, stream>>>(psum1, psq1, bn1_g, bn1_b, ab1, N);

    gemm_mfma_kernel<<<ggrid, 256, 0, stream>>>(nullptr, B1bf, WT2, ab1, Abf, N);
    prop_kernel<<<pgrid, 256, 0, stream>>>((const uint4*)Abf, base, count, esrc,
                                           (const uint4*)B1bf, ab1, (uint4*)B2bf,
                                           psum3, psq3, N, 1);
    reduce_ab_kernel<<<1, 128, 0, stream>>>(psum3, psq3, bn3_g, bn3_b, ab3, N);

    final_kernel<<<fgrid, 256, 0, stream>>>((const unsigned*)B1bf, (const unsigned*)B2bf,
                                            ab1, ab3, out_w, out_b, out, N);
}

// Round 14
// 169.183 us; speedup vs baseline: 1.0261x; 1.0261x over previous
//
#include <hip/hip_runtime.h>
#include <hip/hip_bf16.h>
#include <cstdint>

// ---------------------------------------------------------------------------
// DGNN pipeline, CSR-based aggregation (no scatter atomics on features).
// Biases gcn_b / dcn_b cancel inside the following batchnorms and are skipped.
// R5: MFMA bf16 GEMM. R6: BN folded into consumers; stats fused into props.
// R7: channel-quartered prop -> REGRESSED (XCD replication floor). Reverted.
// R8: packed esrc u32, bf16 B1/B2. R9/R11: gather MLP -> 172.2us.
// R12: depth-8 chains -> NEUTRAL => prop is at its fabric service floor.
//      Reverted to depth-4.
// R13: overlap independent work (single stream serializes it otherwise):
//      fuse1 = convert || wtrans, fuse2 = scatter || gemm1. 14 -> 12 kernels;
//      gemm1 (~13us) + wtrans (~2us) hidden under the CSR build.
// ---------------------------------------------------------------------------

typedef __attribute__((ext_vector_type(8))) short bf16x8;
typedef __attribute__((ext_vector_type(4))) float f32x4;

__device__ __forceinline__ ushort f2bf(float f) {
    union { float f; unsigned u; } c; c.f = f;
    unsigned u = c.u;
    return (ushort)((u + 0x7fffu + ((u >> 16) & 1u)) >> 16);   // RNE
}
__device__ __forceinline__ unsigned pack2bf(float a, float b) {
    return (unsigned)f2bf(a) | ((unsigned)f2bf(b) << 16);
}
__device__ __forceinline__ float bflo(unsigned u) {
    union { unsigned i; float f; } c; c.i = u << 16; return c.f;
}
__device__ __forceinline__ float bfhi(unsigned u) {
    union { unsigned i; float f; } c; c.i = u & 0xffff0000u; return c.f;
}

// Grid-stride 16B zero fill.
__global__ void zero_kernel(uint4* __restrict__ p, int nwords) {
    int i = blockIdx.x * blockDim.x + threadIdx.x;
    if (i < nwords) p[i] = (uint4){0u, 0u, 0u, 0u};
}

// fuse1: blocks [0,cgrid) count destination degrees; blocks [cgrid,cgrid+128)
// transpose both weight matrices to bf16 (independent work, overlapped).
__global__ void fuse1_kernel(const void* __restrict__ ei, int E,
                             int* __restrict__ count, int cgrid,
                             const float* __restrict__ W1, ushort* __restrict__ WT1,
                             const float* __restrict__ W2, ushort* __restrict__ WT2) {
    if (blockIdx.x >= cgrid) {
        int b = blockIdx.x - cgrid;            // 0..127
        const float* W = (b < 64) ? W1 : W2;
        ushort* WT = (b < 64) ? WT1 : WT2;
        int t = (b & 63) * 256 + threadIdx.x;
        int c = t >> 7, k = t & 127;
        WT[t] = f2bf(W[k * 128 + c]);
        return;
    }
    const int* e32 = (const int*)ei;
    bool is64 = ((e32[1] | e32[3] | e32[5] | e32[7]) == 0);
    int stride = cgrid * 256;
    for (int e = blockIdx.x * 256 + threadIdx.x; e < E; e += stride) {
        int c = is64 ? (int)((const long long*)ei)[E + e] : e32[E + e];
        atomicAdd(&count[c], 1);
    }
}

// ---- 3-phase multi-block exclusive scan over count[N] ----
__global__ __launch_bounds__(256) void bsum_kernel(const int* __restrict__ count,
                                                   int* __restrict__ bsum, int n) {
    int t = threadIdx.x;
    int i0 = blockIdx.x * 1024 + t * 4;
    int s = 0;
    if (i0 + 4 <= n) {
        int4 v = *(const int4*)&count[i0];
        s = v.x + v.y + v.z + v.w;
    } else {
        for (int i = i0; i < n; i++) s += count[i];
    }
    __shared__ int ls[256];
    ls[t] = s;
    __syncthreads();
    for (int off = 128; off > 0; off >>= 1) {
        if (t < off) ls[t] += ls[t + off];
        __syncthreads();
    }
    if (t == 0) bsum[blockIdx.x] = ls[0];
}

__global__ void scanb_kernel(int* __restrict__ bsum, int nb) {
    __shared__ int sm[1024];
    int t = threadIdx.x;
    int v = (t < nb) ? bsum[t] : 0;
    sm[t] = v;
    __syncthreads();
    for (int off = 1; off < 1024; off <<= 1) {
        int a = (t >= off) ? sm[t - off] : 0;
        __syncthreads();
        sm[t] += a;
        __syncthreads();
    }
    if (t < nb) bsum[t] = sm[t] - v;   // exclusive
}

__global__ __launch_bounds__(256) void emit_kernel(const int* __restrict__ count,
                                                   const int* __restrict__ bbase,
                                                   int* __restrict__ base, int n) {
    int t = threadIdx.x;
    int i0 = blockIdx.x * 1024 + t * 4;
    int v[4];
    int s = 0;
    if (i0 + 4 <= n) {
        int4 q = *(const int4*)&count[i0];
        v[0] = q.x; v[1] = q.y; v[2] = q.z; v[3] = q.w;
        s = v[0] + v[1] + v[2] + v[3];
    } else {
        #pragma unroll
        for (int k = 0; k < 4; k++) {
            int i = i0 + k;
            v[k] = (i < n) ? count[i] : 0;
            s += v[k];
        }
    }
    __shared__ int sm[256];
    sm[t] = s;
    __syncthreads();
    for (int off = 1; off < 256; off <<= 1) {
        int a = (t >= off) ? sm[t - off] : 0;
        __syncthreads();
        sm[t] += a;
        __syncthreads();
    }
    int run = bbase[blockIdx.x] + sm[t] - s;
    #pragma unroll
    for (int k = 0; k < 4; k++) {
        int i = i0 + k;
        if (i < n) {
            base[i] = run;
            run += v[k];
        }
    }
}

// fuse2: blocks [0,sgrid) scatter packed (deg<<24 | src*64) into esrc using
// base as cursor (base[c] ends at end-offset; prop recovers start = end-cnt);
// blocks [sgrid, sgrid+ggrid) run gemm1 = bf16(x) @ bf16(W1) (independent).
__global__ __launch_bounds__(256) void fuse2_kernel(const void* __restrict__ ei, int E,
                             int* __restrict__ base, const int* __restrict__ count,
                             unsigned* __restrict__ esrc, int sgrid,
                             const float* __restrict__ Xf, const ushort* __restrict__ WT,
                             ushort* __restrict__ Ybf, int n) {
    __shared__ ushort Wl[128 * 136];
    if (blockIdx.x < sgrid) {
        const int* e32 = (const int*)ei;
        bool is64 = ((e32[1] | e32[3] | e32[5] | e32[7]) == 0);
        int stride = sgrid * 256;
        for (int e = blockIdx.x * 256 + threadIdx.x; e < E; e += stride) {
            int r, c;
            if (is64) {
                r = (int)((const long long*)ei)[e];
                c = (int)((const long long*)ei)[E + e];
            } else {
                r = e32[e];
                c = e32[E + e];
            }
            int pos = atomicAdd(&base[c], 1);
            unsigned deg = (unsigned)count[r];
            esrc[pos] = (deg << 24) | ((unsigned)r << 6);
        }
        return;
    }
    // ---- gemm1 body (fp32 input, no affine) ----
    int gb = blockIdx.x - sgrid;
    int t = threadIdx.x;
    for (int idx = t * 8; idx < 128 * 128; idx += 256 * 8) {
        int c = idx >> 7;
        int k = idx & 127;
        *(uint4*)&Wl[c * 136 + k] = *(const uint4*)&WT[idx];
    }
    __syncthreads();

    int wid = t >> 6;
    int lane = t & 63;
    int m0 = gb * 64 + wid * 16;
    if (m0 >= n) return;
    int row = m0 + (lane & 15);
    int rc = row < n ? row : n - 1;
    int kg = (lane >> 4) * 8;

    f32x4 acc[8];
    #pragma unroll
    for (int i = 0; i < 8; i++) acc[i] = (f32x4){0.f, 0.f, 0.f, 0.f};

    #pragma unroll
    for (int ks = 0; ks < 4; ks++) {
        int k0 = ks * 32 + kg;
        const float* xr = &Xf[(size_t)rc * 128];
        float4 lo = *(const float4*)&xr[k0];
        float4 hi = *(const float4*)&xr[k0 + 4];
        bf16x8 a;
        a[0] = (short)f2bf(lo.x); a[1] = (short)f2bf(lo.y);
        a[2] = (short)f2bf(lo.z); a[3] = (short)f2bf(lo.w);
        a[4] = (short)f2bf(hi.x); a[5] = (short)f2bf(hi.y);
        a[6] = (short)f2bf(hi.z); a[7] = (short)f2bf(hi.w);
        #pragma unroll
        for (int nt = 0; nt < 8; nt++) {
            int c = nt * 16 + (lane & 15);
            bf16x8 b = *(bf16x8*)&Wl[c * 136 + k0];
            acc[nt] = __builtin_amdgcn_mfma_f32_16x16x32_bf16(a, b, acc[nt], 0, 0, 0);
        }
    }

    int ro = m0 + (lane >> 4) * 4;
    int co = lane & 15;
    #pragma unroll
    for (int nt = 0; nt < 8; nt++) {
        #pragma unroll
        for (int i = 0; i < 4; i++) {
            int r = ro + i;
            if (r < n) Ybf[(size_t)r * 128 + nt * 16 + co] = f2bf(acc[nt][i]);
        }
    }
}

// gemm2: Y = bf16(ab-affine(bf16 X)) @ bf16(W) via MFMA (BN1 folded).
__global__ __launch_bounds__(256) void gemm_mfma_kernel(const ushort* __restrict__ Xb,
                                                        const ushort* __restrict__ WT,
                                                        const float* __restrict__ ab,
                                                        ushort* __restrict__ Ybf, int n) {
    __shared__ ushort Wl[128 * 136];
    int t = threadIdx.x;
    for (int idx = t * 8; idx < 128 * 128; idx += 256 * 8) {
        int c = idx >> 7;
        int k = idx & 127;
        *(uint4*)&Wl[c * 136 + k] = *(const uint4*)&WT[idx];
    }
    __syncthreads();

    int wid = t >> 6;
    int lane = t & 63;
    int m0 = blockIdx.x * 64 + wid * 16;
    if (m0 >= n) return;
    int row = m0 + (lane & 15);
    int rc = row < n ? row : n - 1;
    int kg = (lane >> 4) * 8;

    f32x4 acc[8];
    #pragma unroll
    for (int i = 0; i < 8; i++) acc[i] = (f32x4){0.f, 0.f, 0.f, 0.f};

    #pragma unroll
    for (int ks = 0; ks < 4; ks++) {
        int k0 = ks * 32 + kg;
        uint4 q = *(const uint4*)&Xb[(size_t)rc * 128 + k0];
        float f0 = bflo(q.x), f1 = bfhi(q.x), f2 = bflo(q.y), f3 = bfhi(q.y);
        float f4 = bflo(q.z), f5 = bfhi(q.z), f6 = bflo(q.w), f7 = bfhi(q.w);
        float4 alo = *(const float4*)&ab[k0];
        float4 ahi = *(const float4*)&ab[k0 + 4];
        float4 blo = *(const float4*)&ab[128 + k0];
        float4 bhi = *(const float4*)&ab[128 + k0 + 4];
        bf16x8 a;
        a[0] = (short)f2bf(alo.x * f0 + blo.x);
        a[1] = (short)f2bf(alo.y * f1 + blo.y);
        a[2] = (short)f2bf(alo.z * f2 + blo.z);
        a[3] = (short)f2bf(alo.w * f3 + blo.w);
        a[4] = (short)f2bf(ahi.x * f4 + bhi.x);
        a[5] = (short)f2bf(ahi.y * f5 + bhi.y);
        a[6] = (short)f2bf(ahi.z * f6 + bhi.z);
        a[7] = (short)f2bf(ahi.w * f7 + bhi.w);
        #pragma unroll
        for (int nt = 0; nt < 8; nt++) {
            int c = nt * 16 + (lane & 15);
            bf16x8 b = *(bf16x8*)&Wl[c * 136 + k0];
            acc[nt] = __builtin_amdgcn_mfma_f32_16x16x32_bf16(a, b, acc[nt], 0, 0, 0);
        }
    }

    int ro = m0 + (lane >> 4) * 4;
    int co = lane & 15;
    #pragma unroll
    for (int nt = 0; nt < 8; nt++) {
        #pragma unroll
        for (int i = 0; i < 4; i++) {
            int r = ro + i;
            if (r < n) Ybf[(size_t)r * 128 + nt * 16 + co] = f2bf(acc[nt][i]);
        }
    }
}

// 4 nodes/wave (quarters), uint4 row parts, depth-4 gather chains (R11-best).
// start = base[node] - count[node] (base holds end offset after scatter).
__global__ __launch_bounds__(256) void prop_kernel(const uint4* __restrict__ XW4,
                            const int* __restrict__ base,
                            const int* __restrict__ count, const unsigned* __restrict__ esrc,
                            const uint4* __restrict__ B1q, const float* __restrict__ ab1,
                            uint4* __restrict__ outq,
                            float* __restrict__ psum, float* __restrict__ psq,
                            int n, int gate) {
    int wave4 = (int)((blockIdx.x * blockDim.x + threadIdx.x) >> 6);
    int lane = threadIdx.x & 63;
    int wid = threadIdx.x >> 6;
    int g = lane >> 4;                 // quarter 0..3
    int p = lane & 15;                 // uint4 part within row
    int node = wave4 * 4 + g;
    bool valid = node < n;
    int nc = valid ? node : n - 1;
    int b = 0, cnt = 0;
    if (valid) { cnt = count[node]; b = base[node] - cnt; }
    float din = rsqrtf((float)(cnt + 1));

    uint4 vs = XW4[(size_t)nc * 16 + p];   // self row (issued early)

    float ax[8];
    #pragma unroll
    for (int k = 0; k < 8; k++) ax[k] = 0.f;

    for (int i = 0; i < cnt; i += 4) {
        unsigned pj[4];
        uint4 vj[4];
        #pragma unroll
        for (int j = 0; j < 4; j++) {
            int e = i + j;
            pj[j] = esrc[b + (e < cnt ? e : cnt - 1)];
        }
        #pragma unroll
        for (int j = 0; j < 4; j++)
            vj[j] = XW4[((pj[j] & 0xFFFFFFu) >> 2) + p];
        #pragma unroll
        for (int j = 0; j < 4; j++) {
            float w = (i + j < cnt) ? rsqrtf((float)((pj[j] >> 24) + 1)) : 0.f;
            ax[0] += w * bflo(vj[j].x); ax[1] += w * bfhi(vj[j].x);
            ax[2] += w * bflo(vj[j].y); ax[3] += w * bfhi(vj[j].y);
            ax[4] += w * bflo(vj[j].z); ax[5] += w * bfhi(vj[j].z);
            ax[6] += w * bflo(vj[j].w); ax[7] += w * bfhi(vj[j].w);
        }
    }

    float sv[8];
    sv[0] = bflo(vs.x); sv[1] = bfhi(vs.x); sv[2] = bflo(vs.y); sv[3] = bfhi(vs.y);
    sv[4] = bflo(vs.z); sv[5] = bfhi(vs.z); sv[6] = bflo(vs.w); sv[7] = bfhi(vs.w);
    #pragma unroll
    for (int k = 0; k < 8; k++) ax[k] = din * (ax[k] + din * sv[k]);

    float vv[8];
    if (gate) {
        uint4 b1 = B1q[(size_t)nc * 16 + p];
        float bv[8];
        bv[0] = bflo(b1.x); bv[1] = bfhi(b1.x); bv[2] = bflo(b1.y); bv[3] = bfhi(b1.y);
        bv[4] = bflo(b1.z); bv[5] = bfhi(b1.z); bv[6] = bflo(b1.w); bv[7] = bfhi(b1.w);
        int c0 = p * 8;
        #pragma unroll
        for (int k = 0; k < 8; k++) {
            float h = ab1[c0 + k] * bv[k] + ab1[128 + c0 + k];
            vv[k] = ax[k] * h;
        }
    } else {
        #pragma unroll
        for (int k = 0; k < 8; k++) vv[k] = ax[k];
    }

    if (valid) {
        uint4 o;
        o.x = pack2bf(vv[0], vv[1]);
        o.y = pack2bf(vv[2], vv[3]);
        o.z = pack2bf(vv[4], vv[5]);
        o.w = pack2bf(vv[6], vv[7]);
        outq[(size_t)node * 16 + p] = o;
    } else {
        #pragma unroll
        for (int k = 0; k < 8; k++) vv[k] = 0.f;
    }

    // stats: sum across the wave's 4 quarters, then across the block's waves.
    float ss[8], qq[8];
    #pragma unroll
    for (int k = 0; k < 8; k++) { ss[k] = vv[k]; qq[k] = vv[k] * vv[k]; }
    #pragma unroll
    for (int k = 0; k < 8; k++) {
        ss[k] += __shfl_xor(ss[k], 16); qq[k] += __shfl_xor(qq[k], 16);
        ss[k] += __shfl_xor(ss[k], 32); qq[k] += __shfl_xor(qq[k], 32);
    }
    __shared__ float sm_s[4][128], sm_q[4][128];
    if (g == 0) {
        int c0 = p * 8;
        #pragma unroll
        for (int k = 0; k < 8; k++) {
            sm_s[wid][c0 + k] = ss[k];
            sm_q[wid][c0 + k] = qq[k];
        }
    }
    __syncthreads();
    if (threadIdx.x < 128) {
        int c = threadIdx.x;
        float s = sm_s[0][c] + sm_s[1][c] + sm_s[2][c] + sm_s[3][c];
        float q2 = sm_q[0][c] + sm_q[1][c] + sm_q[2][c] + sm_q[3][c];
        int slot = (blockIdx.x & 63) * 128;
        atomicAdd(&psum[slot + c], s);
        atomicAdd(&psq[slot + c], q2);
    }
}

// Collapse 64-slot partials into BN affine coefficients: ab[c]=a, ab[128+c]=b.
__global__ void reduce_ab_kernel(const float* __restrict__ psum, const float* __restrict__ psq,
                                 const float* __restrict__ g, const float* __restrict__ beta,
                                 float* __restrict__ ab, int n) {
    int c = threadIdx.x;   // 128 threads
    float s = 0.f, s2 = 0.f;
    for (int r = 0; r < 64; r++) {
        s += psum[r * 128 + c];
        s2 += psq[r * 128 + c];
    }
    float invn = 1.f / (float)n;
    float mu = s * invn;
    float var = s2 * invn - mu * mu;
    float a = g[c] * rsqrtf(var + 1e-5f);
    ab[c] = a;
    ab[128 + c] = beta[c] - mu * a;
}

// result[n] = dot(h[n], ow[0:128]) + dot(BN3(gated[n]), ow[128:256]) + ob
__global__ void final_kernel(const unsigned* __restrict__ B1bf, const unsigned* __restrict__ B2bf,
                             const float* __restrict__ ab1, const float* __restrict__ ab3,
                             const float* __restrict__ ow, const float* __restrict__ ob,
                             float* __restrict__ out, int n) {
    int wave = (int)((blockIdx.x * blockDim.x + threadIdx.x) >> 6);
    int lane = threadIdx.x & 63;
    if (wave >= n) return;
    int c0 = 2 * lane, c1 = c0 + 1;
    unsigned b1 = B1bf[(size_t)wave * 64 + lane];
    unsigned b2 = B2bf[(size_t)wave * 64 + lane];
    float h0 = ab1[c0] * bflo(b1) + ab1[128 + c0];
    float h1 = ab1[c1] * bfhi(b1) + ab1[128 + c1];
    float o0 = ab3[c0] * bflo(b2) + ab3[128 + c0];
    float o1 = ab3[c1] * bfhi(b2) + ab3[128 + c1];
    float partial = h0 * ow[c0] + h1 * ow[c1] + o0 * ow[128 + c0] + o1 * ow[128 + c1];
    #pragma unroll
    for (int off = 32; off > 0; off >>= 1) partial += __shfl_down(partial, off);
    if (lane == 0) out[wave] = partial + ob[0];
}

extern "C" void kernel_launch(void* const* d_in, const int* in_sizes, int n_in,
                              void* d_out, int out_size, void* d_ws, size_t ws_size,
                              hipStream_t stream) {
    const float* x     = (const float*)d_in[0];
    const void*  ei    = d_in[1];
    const float* gcn_w = (const float*)d_in[2];
    const float* bn1_g = (const float*)d_in[4];
    const float* bn1_b = (const float*)d_in[5];
    const float* dcn_w = (const float*)d_in[6];
    const float* bn3_g = (const float*)d_in[8];
    const float* bn3_b = (const float*)d_in[9];
    const float* out_w = (const float*)d_in[10];
    const float* out_b = (const float*)d_in[11];
    float* out = (float*)d_out;

    int N = in_sizes[0] / 128;
    int E = in_sizes[1] / 2;
    size_t N128 = (size_t)N * 128;

    ushort* Abf   = (ushort*)d_ws;           // [N*128] bf16 xw/hw
    ushort* B1bf  = Abf + N128;              // [N*128] bf16 GCN agg (pre-BN)
    ushort* B2bf  = B1bf + N128;             // [N*128] bf16 gated DegGNN out
    unsigned* esrc = (unsigned*)(B2bf + N128); // [E] packed (deg<<24)|(src*64)
    int*   base  = (int*)(esrc + E);         // [N]
    int*   bsum  = base + N;                 // [1024]
    ushort* WT1  = (ushort*)(bsum + 1024);   // [16384] bf16 gcn_w^T
    ushort* WT2  = WT1 + 16384;              // [16384] bf16 dcn_w^T
    float* ab1   = (float*)(WT2 + 16384);    // [256] BN1 a|b
    float* ab3   = ab1 + 256;                // [256] BN3 a|b
    // ---- zeroed region starts here (16B aligned by construction) ----
    int*   count  = (int*)(ab3 + 256);       // [N]
    float* psum1  = (float*)(count + N);     // [64*128]
    float* psq1   = psum1 + 8192;            // [64*128]
    float* psum3  = psq1 + 8192;             // [64*128]
    float* psq3   = psum3 + 8192;            // [64*128]

    size_t zero_bytes = (size_t)((char*)(psq3 + 8192) - (char*)count);
    int zwords = (int)(zero_bytes / 16);
    zero_kernel<<<(zwords + 255) / 256, 256, 0, stream>>>((uint4*)count, zwords);

    int cgrid = (E + 255) / 256;
    if (cgrid > 2048) cgrid = 2048;
    int nb = (N + 1023) / 1024;  // scan blocks
    int ggrid = (N + 63) / 64;   // mfma gemm blocks
    int pgrid = (N + 15) / 16;   // prop: 4 nodes/wave, 4 waves/block
    int fgrid = (N + 3) / 4;     // final: 4 waves/block

    fuse1_kernel<<<cgrid + 128, 256, 0, stream>>>(ei, E, count, cgrid,
                                                  gcn_w, WT1, dcn_w, WT2);
    bsum_kernel<<<nb, 256, 0, stream>>>(count, bsum, N);
    scanb_kernel<<<1, 1024, 0, stream>>>(bsum, nb);
    emit_kernel<<<nb, 256, 0, stream>>>(count, bsum, base, N);
    fuse2_kernel<<<cgrid + ggrid, 256, 0, stream>>>(ei, E, base, count, esrc, cgrid,
                                                    x, WT1, Abf, N);

    prop_kernel<<<pgrid, 256, 0, stream>>>((const uint4*)Abf, base, count, esrc,
                                           nullptr, nullptr, (uint4*)B1bf,
                                           psum1, psq1, N, 0);
    reduce_ab_kernel<<<1, 128, 0, stream>>>(psum1, psq1, bn1_g, bn1_b, ab1, N);

    gemm_mfma_kernel<<<ggrid, 256, 0, stream>>>(B1bf, WT2, ab1, Abf, N);
    prop_kernel<<<pgrid, 256, 0, stream>>>((const uint4*)Abf, base, count, esrc,
                                           (const uint4*)B1bf, ab1, (uint4*)B2bf,
                                           psum3, psq3, N, 1);
    reduce_ab_kernel<<<1, 128, 0, stream>>>(psum3, psq3, bn3_g, bn3_b, ab3, N);

    final_kernel<<<fgrid, 256, 0, stream>>>((const unsigned*)B1bf, (const unsigned*)B2bf,
                                            ab1, ab3, out_w, out_b, out, N);
}